// Round 9
// baseline (667.653 us; speedup 1.0000x reference)
//
#include <hip/hip_runtime.h>

// Nearest-centroid assignment. out[0..N) = max_sim (float), out[N..2N) = argmax (as float).
//
// Decision semantics = round-6 validated np bit-model (einsum baseline-SSE3 unfused
// cascade + AVX512F pairwise norms + fl32 chain + first-max). Fast path: f16x3-split
// MFMA GEMM (hi*hi + hi*lo + lo*hi, fp32 accum), |fast - np| ~ 1e-4 << EPS/2.
// v9: ZERO-REGISTER-PRESSURE design. v3-v8 lost to the register allocator (it targets
// 64-128 VGPR regardless of launch_bounds minima and spills/remats the ~128-reg A-set:
// WRITE_SIZE 9-15 MB scratch signature). Now BOTH operands are pre-split to
// fragment-tiled device globals (g_ctile 1 MB, g_xtile 128 MB) and DMA'd per stage via
// global_load_lds: no conversions, no A-registers, live set ~85 regs -> fits any
// allocator target. A+B double-buffered (64 KB), 2 blocks/CU, counted vmcnt(4),
// barrier/compute/barrier/issue schedule, setprio.
// Margin >= EPS -> winner provably = np winner, recompute np-bit-exactly;
// margin < EPS -> row -> fallback (full np-exact).
constexpr int N = 131072;
constexpr int D = 256;
constexpr int K = 1024;

constexpr int TM = 128;   // rows per block (8 waves x 16 rows)
constexpr int TK = 128;   // centroids per chunk
constexpr float EPS = 0.08f;

typedef _Float16 f16x8 __attribute__((ext_vector_type(8)));
typedef float f32x4 __attribute__((ext_vector_type(4)));

// c pre-split fragment-tiled: [stage=kblk*8+dc][part][kg][krow][e]; 16 KiB/stage;
// 64 real + 2 pad stages (uniform prefetch).
__device__ _Float16 g_ctile[66 * 8192];
// x pre-split fragment-tiled: [blk*8+ds][part][kg][row128][e]; 16 KiB/stage; 128 MiB.
__device__ _Float16 g_xtile[(size_t)1024 * 8 * 8192];

__device__ __forceinline__ float sqf(float a) { return __fmul_rn(a, a); }

// numpy AVX512F pairwise base case over 128 contiguous squares.
__device__ __forceinline__ float np_sumsq128(const float* q) {
    float lane[16];
#pragma unroll
    for (int j = 0; j < 16; j++) {
        const float r0 = __fadd_rn(sqf(q[j]),      sqf(q[64 + j]));
        const float r1 = __fadd_rn(sqf(q[16 + j]), sqf(q[80 + j]));
        const float r2 = __fadd_rn(sqf(q[32 + j]), sqf(q[96 + j]));
        const float r3 = __fadd_rn(sqf(q[48 + j]), sqf(q[112 + j]));
        lane[j] = __fadd_rn(__fadd_rn(r0, r1), __fadd_rn(r2, r3));
    }
    float t[8];
#pragma unroll
    for (int i = 0; i < 8; i++) t[i] = __fadd_rn(lane[i], lane[i + 8]);
    float u[4];
#pragma unroll
    for (int i = 0; i < 4; i++) u[i] = __fadd_rn(t[i], t[i + 4]);
    return __fadd_rn(__fadd_rn(u[0], u[2]), __fadd_rn(u[1], u[3]));
}
__device__ __forceinline__ float np_pw256_sq(const float* p) {
    return __fadd_rn(np_sumsq128(p), np_sumsq128(p + 128));
}

// np einsum bit-exact dot over 256 contiguous floats.
__device__ __forceinline__ float np_dot256(const float* a, const float* b) {
    float A[4] = {0.f, 0.f, 0.f, 0.f};
#pragma unroll 4
    for (int t = 0; t < 16; t++) {
#pragma unroll
        for (int i = 3; i >= 0; i--) {
            const int base = 16 * t + 4 * i;
#pragma unroll
            for (int j = 0; j < 4; j++)
                A[j] = __fadd_rn(A[j], __fmul_rn(a[base + j], b[base + j]));
        }
    }
    return __fadd_rn(__fadd_rn(A[0], A[1]), __fadd_rn(A[2], A[3]));
}

// split one float component into (hi,lo) f16 pair at index idx of vectors he/le
#define SPL(vec, comp, he, le, idx)                                  \
    {                                                                \
        const float fv_ = (vec).comp;                                \
        const _Float16 hh_ = (_Float16)fv_;                          \
        he[idx] = hh_;                                               \
        le[idx] = (_Float16)(fv_ - (float)hh_);                      \
    }

// Fused prep: blocks [0,16384) split x into g_xtile; blocks [16384,16512) split c
// into g_ctile and compute cn. Same fragment-ready layout for both (A/B symmetric).
__global__ __launch_bounds__(256) void prep_kernel(const float* __restrict__ x,
                                                   const float* __restrict__ c,
                                                   float* __restrict__ cn) {
    if (blockIdx.x < 16384) {
        const int idx = blockIdx.x * 256 + threadIdx.x;   // [0, 131072*32)
        const int r = idx >> 5;                            // x row
        const int dslot = idx & 31;                        // ds*4 + kg
        const int ds = dslot >> 2, kg = dslot & 3;
        const float* src = x + (size_t)r * D + ds * 32 + kg * 8;
        const float4 s0 = ((const float4*)src)[0];
        const float4 s1 = ((const float4*)src)[1];
        f16x8 h, l;
        SPL(s0, x, h, l, 0) SPL(s0, y, h, l, 1) SPL(s0, z, h, l, 2) SPL(s0, w, h, l, 3)
        SPL(s1, x, h, l, 4) SPL(s1, y, h, l, 5) SPL(s1, z, h, l, 6) SPL(s1, w, h, l, 7)
        const int blk = r >> 7, rrow = r & 127;
        _Float16* base = g_xtile + (size_t)(blk * 8 + ds) * 8192;
        *(f16x8*)&base[kg * 1024 + rrow * 8]        = h;
        *(f16x8*)&base[4096 + kg * 1024 + rrow * 8] = l;
    } else {
        const int idx = (blockIdx.x - 16384) * 256 + threadIdx.x;   // [0, 32768)
        const int kglob = idx >> 5;                        // centroid row
        const int dslot = idx & 31;
        const int dc = dslot >> 2, kg = dslot & 3;
        const float* src = c + (size_t)kglob * D + dc * 32 + kg * 8;
        const float4 s0 = ((const float4*)src)[0];
        const float4 s1 = ((const float4*)src)[1];
        f16x8 h, l;
        SPL(s0, x, h, l, 0) SPL(s0, y, h, l, 1) SPL(s0, z, h, l, 2) SPL(s0, w, h, l, 3)
        SPL(s1, x, h, l, 4) SPL(s1, y, h, l, 5) SPL(s1, z, h, l, 6) SPL(s1, w, h, l, 7)
        const int kblk = kglob >> 7, krow = kglob & 127;
        _Float16* base = g_ctile + (size_t)(kblk * 8 + dc) * 8192;
        *(f16x8*)&base[kg * 1024 + krow * 8]        = h;
        *(f16x8*)&base[4096 + kg * 1024 + krow * 8] = l;
        if (idx < K) cn[idx] = np_pw256_sq(c + (size_t)idx * D);
    }
}

#define WAITVM(n) asm volatile("s_waitcnt vmcnt(" #n ")" ::: "memory")

__global__ __launch_bounds__(512, 4) void fast_kernel(const float* __restrict__ x,
                                                      const float* __restrict__ c,
                                                      const float* __restrict__ cn,
                                                      float* __restrict__ out,
                                                      int* __restrict__ cnt,
                                                      int* __restrict__ list) {
    __shared__ _Float16 as_[2][8192] __attribute__((aligned(16)));  // A double-buffer
    __shared__ _Float16 cs[2][8192] __attribute__((aligned(16)));   // B double-buffer
    __shared__ float cn_sh[K];
    __shared__ float xn_sh[TM];
    __shared__ int   rbi[TM];
    __shared__ int   rok[TM];

    const int t    = threadIdx.x;
    const int n0   = blockIdx.x * TM;
    const int lane = t & 63;
    const int w    = t >> 6;        // wave id 0..7
    const int wrow = w * 16;        // wave owns rows [wrow, wrow+16)
    const int lr   = lane & 15;     // fragment row/col coordinate
    const int lg   = lane >> 4;     // fragment k-group / C row-group
    const size_t xbase = (size_t)blockIdx.x * 8 * 8192;   // this block's g_xtile slice

    // 512 threads x 2 loads x 16 B = 16 KiB = one stage (per tile)
#define STAGE_B(buf_, sidx_)                                                        \
    {                                                                               \
        const _Float16* gp_ = g_ctile + (size_t)(sidx_) * 8192 + t * 8;             \
        _Float16* lp_ = &cs[buf_][t * 8];                                           \
        __builtin_amdgcn_global_load_lds(                                           \
            (const __attribute__((address_space(1))) void*)gp_,                     \
            (__attribute__((address_space(3))) void*)lp_, 16, 0, 0);                \
        __builtin_amdgcn_global_load_lds(                                           \
            (const __attribute__((address_space(1))) void*)(gp_ + 4096),            \
            (__attribute__((address_space(3))) void*)(lp_ + 4096), 16, 0, 0);       \
    }
#define STAGE_A(buf_, ds_)                                                          \
    {                                                                               \
        const _Float16* gp_ = g_xtile + xbase + (size_t)(ds_) * 8192 + t * 8;       \
        _Float16* lp_ = &as_[buf_][t * 8];                                          \
        __builtin_amdgcn_global_load_lds(                                           \
            (const __attribute__((address_space(1))) void*)gp_,                     \
            (__attribute__((address_space(3))) void*)lp_, 16, 0, 0);                \
        __builtin_amdgcn_global_load_lds(                                           \
            (const __attribute__((address_space(1))) void*)(gp_ + 4096),            \
            (__attribute__((address_space(3))) void*)(lp_ + 4096), 16, 0, 0);       \
    }

    // issue first two stages (A+B each), then overlap prologue work with the DMA
    STAGE_A(0, 0); STAGE_B(0, 0);
    STAGE_A(1, 1); STAGE_B(1, 1);

#pragma unroll
    for (int q = 0; q < 2; q++) cn_sh[t + 512 * q] = cn[t + 512 * q];
    if (t < TM) xn_sh[t] = np_pw256_sq(x + (size_t)(n0 + t) * D);

    float v1[4], v2[4];
    int   i1[4];
#pragma unroll
    for (int s = 0; s < 4; s++) {
        v1[s] = -__builtin_inff(); v2[s] = -__builtin_inff(); i1[s] = 0;
    }

    __syncthreads();   // xn/cn visible; compiler drains all prior vmem (vmcnt 0)

    for (int kb = 0; kb < 8; kb++) {
        f32x4 acc[8];
#pragma unroll
        for (int j = 0; j < 8; j++) acc[j] = (f32x4)(0.f);

#pragma unroll
        for (int dc8 = 0; dc8 < 8; dc8++) {
            const int p = kb * 8 + dc8;           // linear stage index
            WAITVM(4);                            // stage p's 4 loads done (p+1 in flight)
            __builtin_amdgcn_s_barrier();         // all waves' stage-p data in LDS
            __builtin_amdgcn_sched_barrier(0);    // no ds_read hoisting above barrier
            asm volatile("" ::: "memory");

            const _Float16* asb = &as_[dc8 & 1][0];
            const _Float16* csb = &cs[dc8 & 1][0];
            const f16x8 ah = *(const f16x8*)&asb[lg * 1024 + (wrow + lr) * 8];
            const f16x8 al = *(const f16x8*)&asb[4096 + lg * 1024 + (wrow + lr) * 8];
            __builtin_amdgcn_s_setprio(1);
#pragma unroll
            for (int j = 0; j < 8; j++) {
                const f16x8 bh = *(const f16x8*)&csb[lg * 1024 + (16 * j + lr) * 8];
                const f16x8 bl = *(const f16x8*)&csb[4096 + lg * 1024 + (16 * j + lr) * 8];
                acc[j] = __builtin_amdgcn_mfma_f32_16x16x32_f16(ah, bh, acc[j], 0, 0, 0);
                acc[j] = __builtin_amdgcn_mfma_f32_16x16x32_f16(al, bh, acc[j], 0, 0, 0);
                acc[j] = __builtin_amdgcn_mfma_f32_16x16x32_f16(ah, bl, acc[j], 0, 0, 0);
            }
            __builtin_amdgcn_s_setprio(0);
            asm volatile("" ::: "memory");
            __builtin_amdgcn_s_barrier();         // all waves done reading buf dc8&1
            asm volatile("" ::: "memory");
            // refill the just-freed buffer with stage p+2
            STAGE_A(dc8 & 1, (dc8 + 2) & 7);      // A stages cycle d-chunks 0..7
            STAGE_B(dc8 & 1, p + 2);              // B pads 64,65 exist in g_ctile
        }

        // chunk epilogue: C/D layout col = lane&15, row = 4*(lane>>4)+reg (m89-verified).
        // kg ascending within lane (j ascending); first-max kept via strict >.
#pragma unroll
        for (int j = 0; j < 8; j++) {
            const int kg_ = kb * TK + 16 * j + lr;
            const float cnj = cn_sh[kg_];
#pragma unroll
            for (int r = 0; r < 4; r++) {
                const float v = 2.0f * acc[j][r] - xn_sh[wrow + 4 * lg + r] - cnj;
                if (v > v1[r])       { v2[r] = v1[r]; v1[r] = v; i1[r] = kg_; }
                else if (v > v2[r])  { v2[r] = v; }
                else if (v == v1[r]) { v2[r] = v; }  // exact tie -> margin 0
            }
        }
    }

    // merge across the 16 col-lanes (lane&15) per row slot, then decide
#pragma unroll
    for (int r = 0; r < 4; r++) {
        float a1v = v1[r], a2v = v2[r];
        int   ai  = i1[r];
#pragma unroll
        for (int m = 1; m <= 8; m <<= 1) {
            const float ov1 = __shfl_xor(a1v, m);
            const int   oi  = __shfl_xor(ai, m);
            const float ov2 = __shfl_xor(a2v, m);
            if (ov1 > a1v)      { a2v = fmaxf(a1v, ov2); a1v = ov1; ai = oi; }
            else if (ov1 < a1v) { a2v = fmaxf(a2v, ov1); }
            else                { ai = min(ai, oi); a2v = a1v; }
        }
        if (lr == 0) {
            const int row = wrow + 4 * lg + r;
            const int ok = (a1v - a2v >= EPS) ? 1 : 0;
            rbi[row] = ai;
            rok[row] = ok;
            if (!ok) { const int pos = atomicAdd(cnt, 1); list[pos] = n0 + row; }
        }
    }
    __syncthreads();   // drains trailing pad-stage DMA too

    if (t < TM && rok[t]) {
        const int row = n0 + t;
        const int bi  = rbi[t];
        const float dot = np_dot256(x + (size_t)row * D, c + (size_t)bi * D);
        const float v = __fsub_rn(__fsub_rn(__fmul_rn(2.0f, dot), xn_sh[t]), cn[bi]);
        out[row]     = v;
        out[N + row] = (float)bi;
    }
}

__global__ __launch_bounds__(256) void fallback_kernel(const float* __restrict__ x,
                                                       const float* __restrict__ c,
                                                       const float* __restrict__ cn,
                                                       float* __restrict__ out,
                                                       const int* __restrict__ cnt,
                                                       const int* __restrict__ list) {
    __shared__ float xrow[D];
    __shared__ float xn_s;
    __shared__ float wv[4];
    __shared__ int   wi[4];
    const int tid = threadIdx.x, lane = tid & 63, w = tid >> 6;
    const int total = *cnt;
    for (int idx = blockIdx.x; idx < total; idx += gridDim.x) {
        const int row = list[idx];
        if (tid < 64) *(float4*)&xrow[4 * tid] = ((const float4*)(x + (size_t)row * D))[tid];
        __syncthreads();
        if (tid == 0) xn_s = np_pw256_sq(xrow);
        __syncthreads();
        const float xn = xn_s;
        float bv = -__builtin_inff();
        int   bi = 0;
#pragma unroll
        for (int j = 0; j < 4; j++) {
            const int k = 4 * tid + j;  // ascending within thread
            const float dot = np_dot256(xrow, c + (size_t)k * D);
            const float v = __fsub_rn(__fsub_rn(__fmul_rn(2.0f, dot), xn), cn[k]);
            if (v > bv) { bv = v; bi = k; }
        }
#pragma unroll
        for (int m = 1; m <= 32; m <<= 1) {
            const float ov = __shfl_xor(bv, m);
            const int   oi = __shfl_xor(bi, m);
            if (ov > bv || (ov == bv && oi < bi)) { bv = ov; bi = oi; }
        }
        if (lane == 0) { wv[w] = bv; wi[w] = bi; }
        __syncthreads();
        if (tid == 0) {
#pragma unroll
            for (int ww = 1; ww < 4; ww++) {
                if (wv[ww] > bv || (wv[ww] == bv && wi[ww] < bi)) { bv = wv[ww]; bi = wi[ww]; }
            }
            out[row]     = bv;
            out[N + row] = (float)bi;
        }
        __syncthreads();
    }
}

extern "C" void kernel_launch(void* const* d_in, const int* in_sizes, int n_in,
                              void* d_out, int out_size, void* d_ws, size_t ws_size,
                              hipStream_t stream) {
    const float* x = (const float*)d_in[0];
    const float* c = (const float*)d_in[1];
    float* out     = (float*)d_out;
    // ws layout: [0,4096) cn | [4096,4100) count | [4608, ...) flagged-row list
    float* cn = (float*)d_ws;
    int* cnt  = (int*)((char*)d_ws + 4096);
    int* list = (int*)((char*)d_ws + 4608);

    hipMemsetAsync(cnt, 0, sizeof(int), stream);
    prep_kernel<<<16512, 256, 0, stream>>>(x, c, cn);
    fast_kernel<<<N / TM, 512, 0, stream>>>(x, c, cn, out, cnt, list);
    fallback_kernel<<<1024, 256, 0, stream>>>(x, c, cn, out, cnt, list);
}